// Round 8
// baseline (224.902 us; speedup 1.0000x reference)
//
#include <hip/hip_runtime.h>
#include <hip/hip_fp16.h>

// out[n,o,m](l) = sum_i W_l[o,i,m] * x_l[n,i,m];  N=262144, MULT=32, m_l in {1,3,5,7}.
// Streaming: ~1.07GB true HBM traffic per replay (L3 flushed by poison fill);
// floor ~170us (m13 copy bench = same mixed R/W pattern at 6.29 TB/s).
//
// Round-8: TN 32->16, 512->256 threads, 37KB LDS -> 4 blocks/CU (was 2).
// Same 16 waves/CU but 4 independent barrier domains -> desynchronized phases,
// smoother HBM issue (copy-bench-like), cheaper barriers. Structure otherwise
// round-7: 2 lgkm-only barriers/tile, staging -> prefetch -> stores order,
// i-rotation swizzle, W hoisted to regs (2-pass prologue: XT holds 16 o-rows).

#define NTH 256
#define TN  16

typedef _Float16 f16x8 __attribute__((ext_vector_type(8)));
typedef float    f32x4 __attribute__((ext_vector_type(4)));

// LDS-only barrier: order ds ops, leave vmem in flight.
#define LGKM0_BAR() do { asm volatile("s_waitcnt lgkmcnt(0)" ::: "memory"); \
                         __builtin_amdgcn_s_barrier(); } while (0)

// Stage HALF of W_l (16 o-rows starting at src): element e = o'*(32*M_) + i*M_ + mi
//   -> dst[(PB+mi)*640 + o'*40 + ((i + 8*(PB+mi)) & 31)], o' in [0,16)
template<int M_, int PB>
__device__ __forceinline__ void stageWhalf(const float* __restrict__ src,
                                           __half* __restrict__ dst, int tid)
{
    #pragma unroll
    for (int it = 0; it < (128 * M_ + NTH - 1) / NTH; ++it) {
        const int f = tid + it * NTH;
        if (f < 128 * M_) {
            float4 v = ((const float4*)src)[f];
            const float vf[4] = {v.x, v.y, v.z, v.w};
            const int e0 = 4 * f;
            #pragma unroll
            for (int k = 0; k < 4; ++k) {
                const int e = e0 + k;
                const int o = e / (32 * M_);
                const int r = e - o * (32 * M_);
                const int i = r / M_, mi = r - i * M_;
                const int p = PB + mi;
                dst[p * 640 + o * 40 + ((i + 8 * p) & 31)] = __float2half(vf[k]);
            }
        }
    }
}

template<int M_, int PB>
__device__ __forceinline__ void mkoff(int tloc, int* offk)
{
    const int e0    = 4 * tloc;
    const int nodel = e0 / (32 * M_);
    const int r0    = e0 - nodel * (32 * M_);
    #pragma unroll
    for (int k = 0; k < 4; ++k) {
        const int ii = (r0 + k) / M_, mi = (r0 + k) - ii * M_;
        const int p  = PB + mi;
        offk[k] = p * 640 + nodel * 40 + ((ii + 8 * p) & 31);
    }
}

__device__ __forceinline__ void plane_info(int p, int& Mm, int& BASE, int& MI)
{
    if (p == 0)     { Mm = 1; BASE = 0;   MI = 0;     }
    else if (p < 4) { Mm = 3; BASE = 32;  MI = p - 1; }
    else if (p < 9) { Mm = 5; BASE = 128; MI = p - 4; }
    else            { Mm = 7; BASE = 288; MI = p - 9; }
}

__device__ __forceinline__ void store_tile(const __half* __restrict__ OC,
                                           float* __restrict__ dst, int tid)
{
    #pragma unroll
    for (int it = 0; it < 4; ++it) {
        const int d0   = 8 * tid + 2048 * it;
        const int node = d0 >> 9, col = d0 & 511;
        uint4 h8 = *(const uint4*)(OC + node * 520 + col);
        const __half2* hp = (const __half2*)&h8;
        float2 f0 = __half22float2(hp[0]);
        float2 f1 = __half22float2(hp[1]);
        float2 f2 = __half22float2(hp[2]);
        float2 f3 = __half22float2(hp[3]);
        *(float4*)(dst + d0)     = make_float4(f0.x, f0.y, f1.x, f1.y);
        *(float4*)(dst + d0 + 4) = make_float4(f2.x, f2.y, f3.x, f3.y);
    }
}

__global__ __launch_bounds__(NTH, 4) void eqlin(
    const float* __restrict__ x0, const float* __restrict__ x1,
    const float* __restrict__ x2, const float* __restrict__ x3,
    const float* __restrict__ w0, const float* __restrict__ w1,
    const float* __restrict__ w2, const float* __restrict__ w3,
    float* __restrict__ out, int n_tiles)
{
    __shared__ __align__(16) __half XT[10240];   // 20KB: 16 planes x 16 nodes x 40
    __shared__ __align__(16) __half OC[8320];    // 16.6KB: 16 nodes x 520
    const int tid  = threadIdx.x;
    const int wave = tid >> 6;
    const int lane = tid & 63;

    // ---- staging groups: [0,16)->x0, [16,64)->x1, [64,144)->x2, [144,256)->x3
    int thrg, Mg, offk[4];
    const float* xb;
    bool isM1 = false;
    if (tid < 16)       { thrg = 16;  Mg = 1; xb = x0; mkoff<1, 0>(tid,       offk); isM1 = true; }
    else if (tid < 64)  { thrg = 48;  Mg = 3; xb = x1; mkoff<3, 1>(tid - 16,  offk); }
    else if (tid < 144) { thrg = 80;  Mg = 5; xb = x2; mkoff<5, 4>(tid - 64,  offk); }
    else                { thrg = 112; Mg = 7; xb = x3; mkoff<7, 9>(tid - 144, offk); }
    const int  tloc    = (tid < 16) ? tid : (tid < 64) ? tid - 16 : (tid < 144) ? tid - 64 : tid - 144;
    const long jstride = 4L * thrg;                      // floats between j's (= 2 nodes)
    const long tstride = (long)gridDim.x * 512L * Mg;    // floats between my tiles

    // ---- prologue: prefetch tile blockIdx.x (overlaps W staging)
    const float* srcp = xb + (long)blockIdx.x * (512L * Mg) + 4 * tloc;
    float4 pf[8];
    #pragma unroll
    for (int j = 0; j < 8; ++j)
        pf[j] = *(const float4*)(srcp + j * jstride);

    const int lrow = lane & 15;          // A row (node) / B col (o) / C col
    const int lk8  = (lane >> 4) * 8;    // k-chunk (halves)
    const int crow = (lane >> 4) * 4;    // C row base (node)
    const int pA = wave * 4, pB = pA + 1, pC = pA + 2, pD = pA + 3;
    const int cs[4] = { (lk8 + 8 * pA) & 31, (lk8 + 8 * pB) & 31,
                        (lk8 + 8 * pC) & 31, (lk8 + 8 * pD) & 31 };

    // ---- W hoist, 2 passes (XT holds 16 of 32 o-rows per plane)
    f16x8 Wf[4][2];
    #pragma unroll
    for (int half = 0; half < 2; ++half) {
        const int o0 = half * 16;
        stageWhalf<1, 0>(w0 + (long)o0 * 32,  XT, tid);
        stageWhalf<3, 1>(w1 + (long)o0 * 96,  XT, tid);
        stageWhalf<5, 4>(w2 + (long)o0 * 160, XT, tid);
        stageWhalf<7, 9>(w3 + (long)o0 * 224, XT, tid);
        LGKM0_BAR();                     // W half staged
        #pragma unroll
        for (int pl = 0; pl < 4; ++pl)
            Wf[pl][half] = *(const f16x8*)(XT + (pA + pl) * 640 + lrow * 40 + cs[pl]);
        LGKM0_BAR();                     // frag reads done; XT reusable
    }

    int Mm[4], BASE[4], MI[4];
    #pragma unroll
    for (int pl = 0; pl < 4; ++pl) plane_info(pA + pl, Mm[pl], BASE[pl], MI[pl]);

    long prev_node0 = -1;
    for (int t = blockIdx.x; t < n_tiles; t += gridDim.x) {
        const long node0 = (long)t * TN;

        // ======== phase A: staging -> prefetch-loads -> stores ========
        #pragma unroll
        for (int j = 0; j < 8; ++j) {
            const float4 v = pf[j];
            const int jb = j * 80;                   // +2 nodes per j
            if (isM1) {
                __half2* p = (__half2*)&XT[offk[0] + jb];
                p[0] = __floats2half2_rn(v.x, v.y);
                p[1] = __floats2half2_rn(v.z, v.w);
            } else {
                XT[offk[0] + jb] = __float2half(v.x);
                XT[offk[1] + jb] = __float2half(v.y);
                XT[offk[2] + jb] = __float2half(v.z);
                XT[offk[3] + jb] = __float2half(v.w);
            }
        }
        if (t + (long)gridDim.x < n_tiles) {         // prefetch (loads OLDER than stores)
            srcp += tstride;
            #pragma unroll
            for (int j = 0; j < 8; ++j)
                pf[j] = *(const float4*)(srcp + j * jstride);
        }
        if (prev_node0 >= 0)                         // stores of t-1 (youngest vmem)
            store_tile(OC, out + prev_node0 * 512, tid);

        LGKM0_BAR();   // XT staged visible; OC reads done

        // ======== phase B: MFMA + overlay ========
        f32x4 acc[4][2] = {};            // [pl][oh]
        #pragma unroll
        for (int pl = 0; pl < 4; ++pl) {
            f16x8 A = *(const f16x8*)(XT + (pA + pl) * 640 + lrow * 40 + cs[pl]);
            acc[pl][0] = __builtin_amdgcn_mfma_f32_16x16x32_f16(A, Wf[pl][0], acc[pl][0], 0, 0, 0);
            acc[pl][1] = __builtin_amdgcn_mfma_f32_16x16x32_f16(A, Wf[pl][1], acc[pl][1], 0, 0, 0);
        }
        #pragma unroll
        for (int pl = 0; pl < 4; ++pl)
        #pragma unroll
        for (int oh = 0; oh < 2; ++oh) {
            const int o    = oh * 16 + lrow;
            const int colb = BASE[pl] + o * Mm[pl] + MI[pl];
            #pragma unroll
            for (int r = 0; r < 4; ++r)
                OC[(crow + r) * 520 + colb] = __float2half(acc[pl][oh][r]);
        }

        LGKM0_BAR();   // MFMA's XT reads done; OC writes visible
        prev_node0 = node0;
    }

    // ---- epilogue: store last tile
    if (prev_node0 >= 0)
        store_tile(OC, out + prev_node0 * 512, tid);
}

extern "C" void kernel_launch(void* const* d_in, const int* in_sizes, int n_in,
                              void* d_out, int out_size, void* d_ws, size_t ws_size,
                              hipStream_t stream)
{
    // Identify pointers by size: x_l = N*32*m, W_l = 1024*m, m in {1,3,5,7}
    long tot = 0;
    for (int i = 0; i < n_in; ++i) tot += in_sizes[i];
    const long N = (tot - 16384) / 512;
    const int  ms[4] = {1, 3, 5, 7};
    const float* xs[4]  = {nullptr, nullptr, nullptr, nullptr};
    const float* wsp[4] = {nullptr, nullptr, nullptr, nullptr};
    for (int i = 0; i < n_in; ++i) {
        const long s = in_sizes[i];
        for (int l = 0; l < 4; ++l) {
            if (s == N * 32 * ms[l])      xs[l]  = (const float*)d_in[i];
            else if (s == 1024L * ms[l])  wsp[l] = (const float*)d_in[i];
        }
    }
    const int n_tiles = (int)(N / TN);
    const int grid = 1024;                // 4 blocks/CU, persistent, 16 tiles/block
    hipLaunchKernelGGL(eqlin, dim3(grid), dim3(NTH), 0, stream,
                       xs[0], xs[1], xs[2], xs[3],
                       wsp[0], wsp[1], wsp[2], wsp[3],
                       (float*)d_out, n_tiles);
}

// Round 9
// 206.739 us; speedup vs baseline: 1.0879x; 1.0879x over previous
//
#include <hip/hip_runtime.h>
#include <hip/hip_fp16.h>

// out[n,o,m](l) = sum_i W_l[o,i,m] * x_l[n,i,m];  N=262144, MULT=32, m_l in {1,3,5,7}.
// Streaming, ~1.07GB HBM/replay; floor ~170us (m13 6.29TB/s mixed R/W).
//
// Round-9: ONE barrier per tile via parity double-buffering (round-7 = 2).
//   iteration k: stage x(t_k)->XT[k&1] | MFMA(t_{k-1}) from XT[k&1 ^1] |
//                overlay->OC[k&1] | store out(t_{k-2}) from OC[k&1 ^1] | barrier
//   Every buffer hazard is read@k -> write@k+1 separated by one lgkm-barrier.
//   Waves flow through staging/compute/store independently (no block-wide
//   LDS-only windows); vmem order loads-before-stores kept (T4).
// TN=16 @ 512thr: XT 2x20KB + OC 2x16.6KB = 73KB -> 2 blocks/CU, 16 waves/CU
// (same occupancy & tiles/block as round-7; only sync structure changes).

#define NTH 512
#define TN  16

typedef _Float16 f16x8 __attribute__((ext_vector_type(8)));
typedef float    f32x4 __attribute__((ext_vector_type(4)));

// LDS-only barrier: order ds ops, leave vmem in flight.
#define LGKM0_BAR() do { asm volatile("s_waitcnt lgkmcnt(0)" ::: "memory"); \
                         __builtin_amdgcn_s_barrier(); } while (0)

// W stage (prologue only, into contiguous 40KB = both XT buffers):
// element e = o*(32*M_) + i*M_ + mi -> dst[(PB+mi)*1280 + o*40 + ((i+8*(PB+mi))&31)]
template<int M_, int PB>
__device__ __forceinline__ void stageW(const float* __restrict__ src,
                                       __half* __restrict__ dst, int tid)
{
    #pragma unroll
    for (int it = 0; it < (256 * M_ + NTH - 1) / NTH; ++it) {
        const int f = tid + it * NTH;
        if (f < 256 * M_) {
            float4 v = ((const float4*)src)[f];
            const float vf[4] = {v.x, v.y, v.z, v.w};
            const int e0 = 4 * f;
            #pragma unroll
            for (int k = 0; k < 4; ++k) {
                const int e = e0 + k;
                const int o = e / (32 * M_);
                const int r = e - o * (32 * M_);
                const int i = r / M_, mi = r - i * M_;
                const int p = PB + mi;
                dst[p * 1280 + o * 40 + ((i + 8 * p) & 31)] = __float2half(vf[k]);
            }
        }
    }
}

// x-tile offsets (16-node tile, plane stride 640)
template<int M_, int PB>
__device__ __forceinline__ void mkoff(int tloc, int* offk)
{
    const int e0    = 4 * tloc;
    const int nodel = e0 / (32 * M_);
    const int r0    = e0 - nodel * (32 * M_);
    #pragma unroll
    for (int k = 0; k < 4; ++k) {
        const int ii = (r0 + k) / M_, mi = (r0 + k) - ii * M_;
        const int p  = PB + mi;
        offk[k] = p * 640 + nodel * 40 + ((ii + 8 * p) & 31);
    }
}

__device__ __forceinline__ void plane_info(int p, int& Mm, int& BASE, int& MI)
{
    if (p == 0)     { Mm = 1; BASE = 0;   MI = 0;     }
    else if (p < 4) { Mm = 3; BASE = 32;  MI = p - 1; }
    else if (p < 9) { Mm = 5; BASE = 128; MI = p - 4; }
    else            { Mm = 7; BASE = 288; MI = p - 9; }
}

__device__ __forceinline__ void store_tile(const __half* __restrict__ OCb,
                                           float* __restrict__ dst, int tid)
{
    #pragma unroll
    for (int it = 0; it < 2; ++it) {
        const int d0   = 8 * tid + 4096 * it;
        const int node = d0 >> 9, col = d0 & 511;
        uint4 h8 = *(const uint4*)(OCb + node * 520 + col);
        const __half2* hp = (const __half2*)&h8;
        float2 f0 = __half22float2(hp[0]);
        float2 f1 = __half22float2(hp[1]);
        float2 f2 = __half22float2(hp[2]);
        float2 f3 = __half22float2(hp[3]);
        *(float4*)(dst + d0)     = make_float4(f0.x, f0.y, f1.x, f1.y);
        *(float4*)(dst + d0 + 4) = make_float4(f2.x, f2.y, f3.x, f3.y);
    }
}

__global__ __launch_bounds__(NTH, 4) void eqlin(
    const float* __restrict__ x0, const float* __restrict__ x1,
    const float* __restrict__ x2, const float* __restrict__ x3,
    const float* __restrict__ w0, const float* __restrict__ w1,
    const float* __restrict__ w2, const float* __restrict__ w3,
    float* __restrict__ out, int n_tiles)
{
    __shared__ __align__(16) __half XT[2][10240];  // 2x20KB: x planes (parity dbuf)
    __shared__ __align__(16) __half OC[2][8320];   // 2x16.6KB: out overlay (parity dbuf)
    const int tid  = threadIdx.x;
    const int wave = tid >> 6;
    const int lane = tid & 63;

    // ---- staging groups: [0,32)->x0, [32,128)->x1, [128,288)->x2, [288,512)->x3
    int thrg, Mg, offk[4];
    const float* xb;
    bool isM1 = false;
    if (tid < 32)       { thrg = 32;  Mg = 1; xb = x0; mkoff<1, 0>(tid,       offk); isM1 = true; }
    else if (tid < 128) { thrg = 96;  Mg = 3; xb = x1; mkoff<3, 1>(tid - 32,  offk); }
    else if (tid < 288) { thrg = 160; Mg = 5; xb = x2; mkoff<5, 4>(tid - 128, offk); }
    else                { thrg = 224; Mg = 7; xb = x3; mkoff<7, 9>(tid - 288, offk); }
    const int  tloc    = (tid < 32) ? tid : (tid < 128) ? tid - 32 : (tid < 288) ? tid - 128 : tid - 288;
    const long jstride = 4L * thrg;                      // floats between j's (= 4 nodes)
    const long tstride = (long)gridDim.x * 512L * Mg;    // floats between my tiles

    // ---- prologue: prefetch tile blockIdx.x (overlaps W staging)
    const float* srcp = xb + (long)blockIdx.x * (512L * Mg) + 4 * tloc;
    float4 pf[4];
    #pragma unroll
    for (int j = 0; j < 4; ++j)
        pf[j] = *(const float4*)(srcp + j * jstride);

    const int lrow = lane & 15;          // A row (node) / B col (o) / C col
    const int lk8  = (lane >> 4) * 8;    // k-chunk (halves)
    const int crow = (lane >> 4) * 4;    // C row base (node)
    const int p0   = wave * 2, p1 = p0 + 1;
    const int c0   = (lk8 + 8 * p0) & 31;
    const int c1   = (lk8 + 8 * p1) & 31;

    // ---- W hoist (contiguous 40KB across both XT buffers; prologue only)
    __half* WS = &XT[0][0];
    stageW<1, 0>(w0, WS, tid);
    stageW<3, 1>(w1, WS, tid);
    stageW<5, 4>(w2, WS, tid);
    stageW<7, 9>(w3, WS, tid);
    LGKM0_BAR();                         // W staged
    f16x8 Wf[2][2];
    Wf[0][0] = *(const f16x8*)(WS + p0 * 1280 + lrow * 40 + c0);
    Wf[0][1] = *(const f16x8*)(WS + p0 * 1280 + (lrow + 16) * 40 + c0);
    Wf[1][0] = *(const f16x8*)(WS + p1 * 1280 + lrow * 40 + c1);
    Wf[1][1] = *(const f16x8*)(WS + p1 * 1280 + (lrow + 16) * 40 + c1);
    LGKM0_BAR();                         // frag reads done; XT reusable

    int Mm0, BASE0, MI0, Mm1, BASE1, MI1;
    plane_info(p0, Mm0, BASE0, MI0);
    plane_info(p1, Mm1, BASE1, MI1);

    const long gstep = gridDim.x;
    for (long k = 0;; ++k) {
        const long ts  = (long)blockIdx.x + k * gstep;   // tile being staged
        const long tst = ts - 2 * gstep;                 // tile being stored
        const bool do_stage = ts < n_tiles;
        const bool do_mfma  = (k >= 1) && (ts - gstep) < n_tiles;
        const bool do_store = (k >= 2) && tst < n_tiles;
        if (!do_stage && !do_mfma && !do_store) break;
        const int A = (int)(k & 1), B = A ^ 1;

        // ---- stage x(ts) -> XT[A]; prefetch x(ts+gstep)
        if (do_stage) {
            __half* XA = &XT[A][0];
            #pragma unroll
            for (int j = 0; j < 4; ++j) {
                const float4 v = pf[j];
                const int jb = j * 160;                  // +4 nodes per j
                if (isM1) {
                    __half2* p = (__half2*)&XA[offk[0] + jb];
                    p[0] = __floats2half2_rn(v.x, v.y);
                    p[1] = __floats2half2_rn(v.z, v.w);
                } else {
                    XA[offk[0] + jb] = __float2half(v.x);
                    XA[offk[1] + jb] = __float2half(v.y);
                    XA[offk[2] + jb] = __float2half(v.z);
                    XA[offk[3] + jb] = __float2half(v.w);
                }
            }
            if (ts + gstep < n_tiles) {                  // loads OLDER than stores
                srcp += tstride;
                #pragma unroll
                for (int j = 0; j < 4; ++j)
                    pf[j] = *(const float4*)(srcp + j * jstride);
            }
        }

        // ---- store out(tst) from OC[B] (youngest vmem; never waited on)
        if (do_store)
            store_tile(&OC[B][0], out + tst * (TN * 512L), tid);

        // ---- MFMA(ts-gstep) from XT[B]; overlay -> OC[A]
        if (do_mfma) {
            const __half* XB = &XT[B][0];
            f32x4 acc[2][2] = {};        // [pl][oh]
            f16x8 A0 = *(const f16x8*)(XB + p0 * 640 + lrow * 40 + c0);
            f16x8 A1 = *(const f16x8*)(XB + p1 * 640 + lrow * 40 + c1);
            acc[0][0] = __builtin_amdgcn_mfma_f32_16x16x32_f16(A0, Wf[0][0], acc[0][0], 0, 0, 0);
            acc[0][1] = __builtin_amdgcn_mfma_f32_16x16x32_f16(A0, Wf[0][1], acc[0][1], 0, 0, 0);
            acc[1][0] = __builtin_amdgcn_mfma_f32_16x16x32_f16(A1, Wf[1][0], acc[1][0], 0, 0, 0);
            acc[1][1] = __builtin_amdgcn_mfma_f32_16x16x32_f16(A1, Wf[1][1], acc[1][1], 0, 0, 0);

            __half* OA = &OC[A][0];
            #pragma unroll
            for (int pl = 0; pl < 2; ++pl) {
                const int Mm   = pl ? Mm1   : Mm0;
                const int BASE = pl ? BASE1 : BASE0;
                const int MI   = pl ? MI1   : MI0;
                #pragma unroll
                for (int oh = 0; oh < 2; ++oh) {
                    const int o    = oh * 16 + lrow;
                    const int colb = BASE + o * Mm + MI;
                    #pragma unroll
                    for (int r = 0; r < 4; ++r)
                        OA[(crow + r) * 520 + colb] = __float2half(acc[pl][oh][r]);
                }
            }
        }

        LGKM0_BAR();   // single sync point per tile
    }
}

extern "C" void kernel_launch(void* const* d_in, const int* in_sizes, int n_in,
                              void* d_out, int out_size, void* d_ws, size_t ws_size,
                              hipStream_t stream)
{
    // Identify pointers by size: x_l = N*32*m, W_l = 1024*m, m in {1,3,5,7}
    long tot = 0;
    for (int i = 0; i < n_in; ++i) tot += in_sizes[i];
    const long N = (tot - 16384) / 512;
    const int  ms[4] = {1, 3, 5, 7};
    const float* xs[4]  = {nullptr, nullptr, nullptr, nullptr};
    const float* wsp[4] = {nullptr, nullptr, nullptr, nullptr};
    for (int i = 0; i < n_in; ++i) {
        const long s = in_sizes[i];
        for (int l = 0; l < 4; ++l) {
            if (s == N * 32 * ms[l])      xs[l]  = (const float*)d_in[i];
            else if (s == 1024L * ms[l])  wsp[l] = (const float*)d_in[i];
        }
    }
    const int n_tiles = (int)(N / TN);
    const int grid = 512;                 // 2 blocks/CU, persistent, 32 tiles/block
    hipLaunchKernelGGL(eqlin, dim3(grid), dim3(NTH), 0, stream,
                       xs[0], xs[1], xs[2], xs[3],
                       wsp[0], wsp[1], wsp[2], wsp[3],
                       (float*)d_out, n_tiles);
}